// Round 5
// baseline (479.571 us; speedup 1.0000x reference)
//
#include <hip/hip_runtime.h>
#include <stdint.h>

// ---------------------------------------------------------------------------
// NeuralEmbeddingLayer: patchify -> GEMM1(+bias,gelu,x32) -> GEMM2(+bias,+pos)
// R6: faithful port of the verified 256^2 8-phase schedule (m201 template):
//  - 8 waves (2Mx4N), per-wave 128x64 (acc[8][4]), BK=64
//  - LDS = 4 circular half-tile slots per matrix (4 x 128x64 = 64KB each,
//    128KB total). Half-tiles: A-lo/A-hi = tile rows 0-127/128-255 (B same).
//    Tile t's A-lo -> slot (2t)&3, A-hi -> slot (2t+1)&3. Overwrite distance
//    = 2 tiles; reads of tile t close at p2's barrier -> p3/p4 stages safe.
//  - 4 phases per K-tile: p1{read a[0-3],b[0-3] (16 ds_read); stage; bar;
//    lgkm0; 16 MFMA; bar} p2{read a[4-7]; bar; lgkm0; 16 MFMA; bar}
//    p3{stage x2; bar; 16 MFMA; bar} p4{stage; vmcnt(6); bar; 16 MFMA; bar}
//  - 1 half-tile staged per phase, 3 in flight, vmcnt(6) once per tile
//    (never 0 mid-loop; 0 only at the final boundary).
//  - data path (XOR swizzle, fragments, epilogue, XCD swizzle) = verified.
// ---------------------------------------------------------------------------

typedef __attribute__((ext_vector_type(8))) short bf16x8;   // 8 bf16 = 4 VGPRs
typedef __attribute__((ext_vector_type(4))) float f32x4;    // MFMA C/D frag

#define VMCNT(n) asm volatile("s_waitcnt vmcnt(" #n ")" ::: "memory")
#define LGKM0()  asm volatile("s_waitcnt lgkmcnt(0)" ::: "memory")
#define CFENCE() asm volatile("" ::: "memory")
#define BARRIER() do { CFENCE(); __builtin_amdgcn_s_barrier(); CFENCE(); } while (0)

__device__ __forceinline__ unsigned short f2bf(float f) {
  union { float f; unsigned u; } v; v.f = f;
  const unsigned u = v.u;
  return (unsigned short)((u + 0x7fffu + ((u >> 16) & 1u)) >> 16);  // RNE
}

__device__ __forceinline__ float gelu_exact(float x) {
  return 0.5f * x * (1.0f + erff(x * 0.70710678118654752440f));
}

// async global->LDS, 16B per lane. HW writes lds_base(lane0) + lane*16.
__device__ __forceinline__ void gl_lds16(const unsigned short* g, unsigned short* l) {
  __builtin_amdgcn_global_load_lds(
      (const __attribute__((address_space(1))) unsigned int*)g,
      (__attribute__((address_space(3))) unsigned int*)l, 16, 0, 0);
}

// --------------------------- prep kernels ----------------------------------

__global__ void cast_f32_bf16(const float* __restrict__ src,
                              unsigned short* __restrict__ dst, int n) {
  const int i = blockIdx.x * 256 + threadIdx.x;
  if (i < n) dst[i] = f2bf(src[i]);
}

// spikes [32][512][1024] f32 -> patches bf16 [32768][512]
__global__ void patchify(const float* __restrict__ spikes,
                         unsigned short* __restrict__ P) {
  const int idx = blockIdx.x * 256 + threadIdx.x;
  const int m = idx >> 7;
  const int c = (idx & 127) << 2;
  const int b = m >> 10, p = m & 1023;
  const int pt = p >> 5, ps = p & 31;
  const int ft = c >> 5, fs = c & 31;
  const float4 v = *(const float4*)(spikes +
      (size_t)(((b << 9) + pt * 16 + ft) << 10) + ps * 32 + fs);
  ushort4 o;
  o.x = f2bf(v.x); o.y = f2bf(v.y); o.z = f2bf(v.z); o.w = f2bf(v.w);
  *(ushort4*)(P + (size_t)m * 512 + c) = o;
}

// G rows b*1025 = gelu(cls)*32 (cls skips b_embed); zero pad rows [32800,32896)
__global__ void g0_and_pad(const float* __restrict__ cls,
                           unsigned short* __restrict__ G) {
  const int i = blockIdx.x * 256 + threadIdx.x;  // 98304 threads
  G[(size_t)32800 * 1024 + i] = 0;
  if (i < 1024) {
    const unsigned short bv = f2bf(gelu_exact(cls[i]) * 32.0f);
    for (int b = 0; b < 32; ++b) G[(size_t)(b * 1025) * 1024 + i] = bv;
  }
}

__global__ void mask_stamp(float* __restrict__ out) {
  const int i = blockIdx.x * 256 + threadIdx.x;
  if (i < 32800) {
    out[33587200 + i] = 1.0f;
    out[33587200 + 32800 + i] = (float)(i % 1025);
  }
}

// --------------------------- staging ---------------------------------------
// Unified half-tile index u: tile t = u>>2; u&3: 0=A-lo 1=B-lo 2=A-hi 3=B-hi.
// Slot = (2t + hi) & 3, 8192 elems each. Within a half: granule g = l*512+tid
// (lane-linear), row r = g>>3 in [0,128), slot8 = g&7, holds global k-chunk
// slot8 ^ (r&7). 2 gl_lds per thread per half-tile (16 KB).
__device__ __forceinline__ void stage_half(
    int u, const unsigned short* __restrict__ A,
    const unsigned short* __restrict__ B, int K, int rowStart, int colStart,
    int rmax, int tid, unsigned short* lsA, unsigned short* lsB) {
  const int t = u >> 2;
  const int wch = u & 3;
  const int hi = wch >> 1;
  unsigned short* dst = ((wch & 1) ? lsB : lsA) + (((2 * t + hi) & 3) << 13);
  const unsigned short* src = (wch & 1) ? B : A;
  const int base = ((wch & 1) ? colStart : rowStart) + (hi << 7);
  const int k0 = t << 6;
#pragma unroll
  for (int l = 0; l < 2; ++l) {
    const int g = l * 512 + tid;
    const int r = g >> 3;
    const int s8 = g & 7;
    const int kc = (s8 ^ (r & 7)) << 3;
    int row = base + r;
    if (!(wch & 1) && row > rmax) row = rmax;  // GEMM2 tail: clamp to zero rows
    gl_lds16(src + (size_t)row * K + (k0 + kc), dst + g * 8);
  }
}

// --------------------------- NT GEMM core ----------------------------------
// C[M,N] = A[M,K]*B[N,K]^T. 256x256 tile, BK=64, 8 waves x (8x4) 16x16x32 mfma.
template <int K, bool GELU_EPI>
__global__ __launch_bounds__(512, 2) void gemm_bt(
    const unsigned short* __restrict__ A, const unsigned short* __restrict__ B,
    const float* __restrict__ bias, unsigned short* __restrict__ Cg,
    float* __restrict__ Cf, const float* __restrict__ pos,
    int Mvalid, int rmax, int nRowBlk) {
  __shared__ __align__(16) unsigned short lsA[32768];   // 4 slots x 16 KB
  __shared__ __align__(16) unsigned short lsB[32768];   // 4 slots x 16 KB
  constexpr int NT = K / 64;
  constexpr int NH = 4 * NT;

  const int tid = threadIdx.x;
  const int lane = tid & 63;
  const int w = tid >> 6;
  const int quad = lane >> 4;
  const int l16 = lane & 15;
  const int wm = (w >> 2) * 128;   // wave row offset: 0 or 128 (A-half = w>>2)
  const int wn = (w & 3) * 64;     // wave col offset (B-half = (w>>1)&1)

  // bijective XCD swizzle (m204); row-major so the 4 col-blocks sharing an
  // A-band are contiguous within one XCD's chunk.
  const int nwg = nRowBlk * 4;
  const int q = nwg >> 3, rr = nwg & 7;
  const int xcd = blockIdx.x & 7, jj = blockIdx.x >> 3;
  const int wgid =
      (xcd < rr ? xcd * (q + 1) : rr * (q + 1) + (xcd - rr) * q) + jj;
  const int rowStart = (wgid >> 2) << 8;
  const int colStart = (wgid & 3) << 8;

  f32x4 acc[8][4];
  const f32x4 z = {0.f, 0.f, 0.f, 0.f};
#pragma unroll
  for (int i = 0; i < 8; ++i)
#pragma unroll
    for (int j = 0; j < 4; ++j) acc[i][j] = z;

  // prologue: halves u=0..6 (tile0 complete + tile1's first 3); wait so that
  // tile0 (first 4 halves) has landed: <=3 halves (6 loads) outstanding.
  for (int u = 0; u < 7; ++u)
    stage_half(u, A, B, K, rowStart, colStart, rmax, tid, lsA, lsB);
  VMCNT(6);
  BARRIER();

  // fragment read bases. slot8 = k_chunk ^ (r&7); r&7 == l16&7.
  const int abase = l16 << 6;                      // (i*16+l16)*64 = i*1024+...
  const int bbase = ((wn & 64) + l16) << 6;        // within-half B row
  const int sl0 = (quad ^ (l16 & 7)) << 3;         // kk=0 : chunk = quad
  const int sl1 = ((4 + quad) ^ (l16 & 7)) << 3;   // kk=32: chunk = 4+quad

  for (int t = 0; t < NT; ++t) {
    const unsigned short* pa = lsA + (((2 * t + (w >> 2)) & 3) << 13) + abase;
    const unsigned short* pb = lsB + (((2 * t + ((w >> 1) & 1)) & 3) << 13) + bbase;
    bf16x8 a[8][2], b[4][2];

    // ---- p1: read a[0-3], b[0-3]; stage t+1's last half; MFMA i0-3 x j0-1 --
#pragma unroll
    for (int i = 0; i < 4; ++i) {
      a[i][0] = *(const bf16x8*)(pa + i * 1024 + sl0);
      a[i][1] = *(const bf16x8*)(pa + i * 1024 + sl1);
    }
#pragma unroll
    for (int j = 0; j < 4; ++j) {
      b[j][0] = *(const bf16x8*)(pb + j * 1024 + sl0);
      b[j][1] = *(const bf16x8*)(pb + j * 1024 + sl1);
    }
    if (4 * t + 7 < NH)
      stage_half(4 * t + 7, A, B, K, rowStart, colStart, rmax, tid, lsA, lsB);
    BARRIER();
    LGKM0();
    __builtin_amdgcn_s_setprio(1);
#pragma unroll
    for (int i = 0; i < 4; ++i)
#pragma unroll
      for (int j = 0; j < 2; ++j) {
        acc[i][j] = __builtin_amdgcn_mfma_f32_16x16x32_bf16(a[i][0], b[j][0], acc[i][j], 0, 0, 0);
        acc[i][j] = __builtin_amdgcn_mfma_f32_16x16x32_bf16(a[i][1], b[j][1], acc[i][j], 0, 0, 0);
      }
    __builtin_amdgcn_s_setprio(0);
    BARRIER();

    // ---- p2: read a[4-7]; MFMA i0-3 x j2-3 (regs from p1) ------------------
#pragma unroll
    for (int i = 4; i < 8; ++i) {
      a[i][0] = *(const bf16x8*)(pa + i * 1024 + sl0);
      a[i][1] = *(const bf16x8*)(pa + i * 1024 + sl1);
    }
    BARRIER();
    LGKM0();   // after this, ALL tile-t LDS reads are in regs -> slots free
    __builtin_amdgcn_s_setprio(1);
#pragma unroll
    for (int i = 0; i < 4; ++i)
#pragma unroll
      for (int j = 2; j < 4; ++j) {
        acc[i][j] = __builtin_amdgcn_mfma_f32_16x16x32_bf16(a[i][0], b[j][0], acc[i][j], 0, 0, 0);
        acc[i][j] = __builtin_amdgcn_mfma_f32_16x16x32_bf16(a[i][1], b[j][1], acc[i][j], 0, 0, 0);
      }
    __builtin_amdgcn_s_setprio(0);
    BARRIER();

    // ---- p3: stage 2 halves of t+2 (slots freed at p2 close); MFMA i4-7 j0-1
    if (4 * t + 8 < NH)
      stage_half(4 * t + 8, A, B, K, rowStart, colStart, rmax, tid, lsA, lsB);
    if (4 * t + 9 < NH)
      stage_half(4 * t + 9, A, B, K, rowStart, colStart, rmax, tid, lsA, lsB);
    BARRIER();
    __builtin_amdgcn_s_setprio(1);
#pragma unroll
    for (int i = 4; i < 8; ++i)
#pragma unroll
      for (int j = 0; j < 2; ++j) {
        acc[i][j] = __builtin_amdgcn_mfma_f32_16x16x32_bf16(a[i][0], b[j][0], acc[i][j], 0, 0, 0);
        acc[i][j] = __builtin_amdgcn_mfma_f32_16x16x32_bf16(a[i][1], b[j][1], acc[i][j], 0, 0, 0);
      }
    __builtin_amdgcn_s_setprio(0);
    BARRIER();

    // ---- p4: stage 1 half of t+2; boundary vmcnt; MFMA i4-7 x j2-3 ---------
    if (4 * t + 10 < NH)
      stage_half(4 * t + 10, A, B, K, rowStart, colStart, rmax, tid, lsA, lsB);
    if (t < NT - 2) { VMCNT(6); }        // tile t+1 landed; 3 halves in flight
    else if (t == NT - 2) { VMCNT(0); }  // final drain: tile NT-1 landed
    BARRIER();
    __builtin_amdgcn_s_setprio(1);
#pragma unroll
    for (int i = 4; i < 8; ++i)
#pragma unroll
      for (int j = 2; j < 4; ++j) {
        acc[i][j] = __builtin_amdgcn_mfma_f32_16x16x32_bf16(a[i][0], b[j][0], acc[i][j], 0, 0, 0);
        acc[i][j] = __builtin_amdgcn_mfma_f32_16x16x32_bf16(a[i][1], b[j][1], acc[i][j], 0, 0, 0);
      }
    __builtin_amdgcn_s_setprio(0);
    BARRIER();
  }

  // ---------------------------- epilogue ------------------------------------
#pragma unroll
  for (int i = 0; i < 8; ++i) {
    const int rb = rowStart + wm + i * 16 + quad * 4;
#pragma unroll
    for (int j = 0; j < 4; ++j) {
      const int gc = colStart + wn + j * 16 + l16;
      const float bv = bias[gc];
#pragma unroll
      for (int r = 0; r < 4; ++r) {
        const int row = rb + r;
        float v = acc[i][j][r] + bv;
        if (GELU_EPI) {
          v = gelu_exact(v) * 32.0f;
          const int grow = row + (row >> 10) + 1;   // b*1024+p -> b*1025+p+1
          Cg[(size_t)grow * 1024 + gc] = f2bf(v);
        } else {
          if (row < Mvalid) {
            const int p = row % 1025;               // magic-mul, cheap
            Cf[(size_t)row * 1024 + gc] = v + pos[(size_t)p * 1024 + gc];
          }
        }
      }
    }
  }
}

// --------------------------- launcher --------------------------------------

extern "C" void kernel_launch(void* const* d_in, const int* in_sizes, int n_in,
                              void* d_out, int out_size, void* d_ws, size_t ws_size,
                              hipStream_t stream) {
  const float* spikes  = (const float*)d_in[0];
  const float* W_embed = (const float*)d_in[1];
  const float* b_embed = (const float*)d_in[2];
  const float* cls     = (const float*)d_in[3];
  const float* W_proj  = (const float*)d_in[4];
  const float* b_proj  = (const float*)d_in[5];
  const float* pos     = (const float*)d_in[6];
  float* out = (float*)d_out;

  char* ws = (char*)d_ws;
  unsigned short* P  = (unsigned short*)(ws);              // 32 MiB
  unsigned short* G  = (unsigned short*)(ws + 33554432);   // 64.25 MiB
  unsigned short* WE = (unsigned short*)(ws + 100925440);  // 1 MiB
  unsigned short* WP = (unsigned short*)(ws + 101974016);  // 2 MiB

  hipLaunchKernelGGL(cast_f32_bf16, dim3(2048), dim3(256), 0, stream, W_embed, WE, 524288);
  hipLaunchKernelGGL(cast_f32_bf16, dim3(4096), dim3(256), 0, stream, W_proj, WP, 1048576);
  hipLaunchKernelGGL(patchify, dim3(16384), dim3(256), 0, stream, spikes, P);
  hipLaunchKernelGGL(g0_and_pad, dim3(384), dim3(256), 0, stream, cls, G);
  hipLaunchKernelGGL(mask_stamp, dim3(129), dim3(256), 0, stream, out);

  // GEMM1: [32768,512] x [1024,512]^T -> gelu*32 -> G (bf16). 128x4 = 512 blocks.
  hipLaunchKernelGGL((gemm_bt<512, true>), dim3(512), dim3(512), 0, stream,
                     P, WE, b_embed, G, (float*)nullptr, (const float*)nullptr,
                     0, 32767, 128);
  // GEMM2: [32896,1024] x [1024,1024]^T -> +b_proj +pos -> out (f32).
  // 129x4 = 516 blocks; tail row-block clamps A reads into zeroed rows.
  hipLaunchKernelGGL((gemm_bt<1024, false>), dim3(516), dim3(512), 0, stream,
                     G, WP, b_proj, (unsigned short*)nullptr, out, pos,
                     32800, 32895, 129);
}

// Round 6
// 397.313 us; speedup vs baseline: 1.2070x; 1.2070x over previous
//
#include <hip/hip_runtime.h>
#include <stdint.h>

// ---------------------------------------------------------------------------
// NeuralEmbeddingLayer: patchify+GEMM1 fused (+bias,gelu,x32) -> GEMM2(+bias,+pos)
// R7 (vs R4, the best measured):
//  - patchify kernel DELETED: GEMM1 stages A by gathering 8-contiguous f32
//    directly from spikes (reg-stage: loads issued pre-compute, vmcnt(0) +
//    cvt + ds_write post-barrier = T14 latency hiding). Saves a 30 µs pass
//    and the 64 MB P round-trip.
//  - epilogues reordered rows-outer: %1025 / row pointers / bias hoisted
//    (was per-element: ~128 mod+mul per thread -> 16).
//  - GEMM2 K-loop, swizzle, staging = R4 VERBATIM (best measured structure).
// ---------------------------------------------------------------------------

typedef __attribute__((ext_vector_type(8))) short bf16x8;   // 8 bf16 = 4 VGPRs
typedef __attribute__((ext_vector_type(4))) float f32x4;    // MFMA C/D frag

#define VMCNT(n) asm volatile("s_waitcnt vmcnt(" #n ")" ::: "memory")
#define LGKM0()  asm volatile("s_waitcnt lgkmcnt(0)" ::: "memory")
#define CFENCE() asm volatile("" ::: "memory")

__device__ __forceinline__ unsigned short f2bf(float f) {
  union { float f; unsigned u; } v; v.f = f;
  const unsigned u = v.u;
  return (unsigned short)((u + 0x7fffu + ((u >> 16) & 1u)) >> 16);  // RNE
}

__device__ __forceinline__ float gelu_exact(float x) {
  return 0.5f * x * (1.0f + erff(x * 0.70710678118654752440f));
}

// async global->LDS, 16B per lane. HW writes lds_base(lane0) + lane*16.
__device__ __forceinline__ void gl_lds16(const unsigned short* g, unsigned short* l) {
  __builtin_amdgcn_global_load_lds(
      (const __attribute__((address_space(1))) unsigned int*)g,
      (__attribute__((address_space(3))) unsigned int*)l, 16, 0, 0);
}

// --------------------------- prep kernels ----------------------------------

__global__ void cast_f32_bf16(const float* __restrict__ src,
                              unsigned short* __restrict__ dst, int n) {
  const int i = blockIdx.x * 256 + threadIdx.x;
  if (i < n) dst[i] = f2bf(src[i]);
}

// G rows b*1025 = gelu(cls)*32 (cls skips b_embed); zero pad rows [32800,32896)
__global__ void g0_and_pad(const float* __restrict__ cls,
                           unsigned short* __restrict__ G) {
  const int i = blockIdx.x * 256 + threadIdx.x;  // 98304 threads
  G[(size_t)32800 * 1024 + i] = 0;
  if (i < 1024) {
    const unsigned short bv = f2bf(gelu_exact(cls[i]) * 32.0f);
    for (int b = 0; b < 32; ++b) G[(size_t)(b * 1025) * 1024 + i] = bv;
  }
}

__global__ void mask_stamp(float* __restrict__ out) {
  const int i = blockIdx.x * 256 + threadIdx.x;
  if (i < 32800) {
    out[33587200 + i] = 1.0f;
    out[33587200 + 32800 + i] = (float)(i % 1025);
  }
}

// --------------------------- GEMM1 (fused patchify) ------------------------
// C[32768,1024] = A[32768,512] x WE[1024,512]^T; A gathered from spikes f32.
// A row m: b=m>>10, p=m&1023, pt=p>>5, ps=p&31. A col c: ft=c>>5, fs=c&31.
// A[m][c] = spikes[((b<<9)+(pt<<4)+ft)<<10) + (ps<<5)+fs]; an 8-elem k-chunk
// (c0 = 8*chunk) is 8 CONTIGUOUS f32. Per K-tile c0 += 64 -> +2048 floats.
// LDS granule g: r=g>>3, slot=g&7 holds chunk slot^(r&7) (R4 layout).
__global__ __launch_bounds__(256) void gemm1_fused(
    const float* __restrict__ spikes, const unsigned short* __restrict__ Bw,
    const float* __restrict__ bias, unsigned short* __restrict__ G) {
  __shared__ __align__(16) unsigned short lsA[2][8192];   // 2 x 16 KB
  __shared__ __align__(16) unsigned short lsB[2][8192];
  const int tid = threadIdx.x;
  const int lane = tid & 63;
  const int w = tid >> 6;
  const int quad = lane >> 4;
  const int l16 = lane & 15;

  // XCD-locality swizzle (R2/R4-verified)
  const int L = blockIdx.x;
  const int xcd = L & 7;
  const int j = L >> 3;
  const int rowBlk = xcd * 32 + (j >> 3), colBlk = j & 7;
  const int rowStart = rowBlk * 128;
  const int colStart = colBlk * 128;
  const int wm = (w >> 1) * 64;
  const int wn = (w & 1) * 64;

  f32x4 acc[4][4];
  const f32x4 z = {0.f, 0.f, 0.f, 0.f};
#pragma unroll
  for (int i = 0; i < 4; ++i)
#pragma unroll
    for (int j2 = 0; j2 < 4; ++j2) acc[i][j2] = z;

  const int g0 = w * 256 + lane;
  unsigned aoff[4];      // f32-element offset into spikes for tile 0
  int bRow[4], bKc[4], ldsOff[4];
#pragma unroll
  for (int s = 0; s < 4; ++s) {
    const int g = g0 + s * 64, r = g >> 3, slot = g & 7;
    const int m = rowStart + r, b = m >> 10, p = m & 1023;
    const int pt = p >> 5, ps = p & 31;
    const int chunk = slot ^ (r & 7);
    aoff[s] = (unsigned)((((b << 9) + (pt << 4) + (chunk >> 2)) << 10) +
                         (ps << 5) + ((chunk & 3) << 3));
    bRow[s] = colStart + r;
    bKc[s] = chunk << 3;
    ldsOff[s] = g * 8;
  }

  float4 ar[8];
  // prologue: tile 0 -> buffer 0
#pragma unroll
  for (int s = 0; s < 4; ++s) {
    const float* sp = spikes + aoff[s];
    ar[2 * s] = *(const float4*)(sp);
    ar[2 * s + 1] = *(const float4*)(sp + 4);
    gl_lds16(Bw + (size_t)bRow[s] * 512 + bKc[s], lsB[0] + ldsOff[s]);
  }
  VMCNT(0);
#pragma unroll
  for (int s = 0; s < 4; ++s) {
    union { unsigned short u[8]; bf16x8 v; } pk;
    pk.u[0] = f2bf(ar[2 * s].x); pk.u[1] = f2bf(ar[2 * s].y);
    pk.u[2] = f2bf(ar[2 * s].z); pk.u[3] = f2bf(ar[2 * s].w);
    pk.u[4] = f2bf(ar[2 * s + 1].x); pk.u[5] = f2bf(ar[2 * s + 1].y);
    pk.u[6] = f2bf(ar[2 * s + 1].z); pk.u[7] = f2bf(ar[2 * s + 1].w);
    *(bf16x8*)(lsA[0] + ldsOff[s]) = pk.v;
  }
  LGKM0();
  CFENCE(); __builtin_amdgcn_s_barrier(); CFENCE();

  for (int t = 0; t < 8; ++t) {
    const int cur = t & 1;
    const bool pf = (t < 7);
    if (pf) {
      // issue next tile's A (regs) + B (gl_lds) EARLY; latency hides under
      // this tile's compute (T14 split).
#pragma unroll
      for (int s = 0; s < 4; ++s) {
        const float* sp = spikes + aoff[s] + (unsigned)(t + 1) * 2048u;
        ar[2 * s] = *(const float4*)(sp);
        ar[2 * s + 1] = *(const float4*)(sp + 4);
        gl_lds16(Bw + (size_t)bRow[s] * 512 + ((t + 1) << 6) + bKc[s],
                 lsB[cur ^ 1] + ldsOff[s]);
      }
    }

    const unsigned short* cA = lsA[cur];
    const unsigned short* cB = lsB[cur];
#pragma unroll
    for (int kk = 0; kk < 64; kk += 32) {
      bf16x8 af[4], bfr[4];
      const int kcb = (kk >> 3) + quad;
#pragma unroll
      for (int i = 0; i < 4; ++i) {
        const int r = wm + i * 16 + l16;
        af[i] = *(const bf16x8*)(cA + r * 64 + ((kcb ^ (r & 7)) << 3));
      }
#pragma unroll
      for (int j2 = 0; j2 < 4; ++j2) {
        const int r = wn + j2 * 16 + l16;
        bfr[j2] = *(const bf16x8*)(cB + r * 64 + ((kcb ^ (r & 7)) << 3));
      }
#pragma unroll
      for (int i = 0; i < 4; ++i)
#pragma unroll
        for (int j2 = 0; j2 < 4; ++j2)
          acc[i][j2] = __builtin_amdgcn_mfma_f32_16x16x32_bf16(af[i], bfr[j2],
                                                               acc[i][j2], 0, 0, 0);
    }

    CFENCE(); __builtin_amdgcn_s_barrier(); CFENCE();  // close reads of cur
    if (pf) {
      VMCNT(0);   // A regs + B gl_lds landed (hidden under compute)
#pragma unroll
      for (int s = 0; s < 4; ++s) {
        union { unsigned short u[8]; bf16x8 v; } pk;
        pk.u[0] = f2bf(ar[2 * s].x); pk.u[1] = f2bf(ar[2 * s].y);
        pk.u[2] = f2bf(ar[2 * s].z); pk.u[3] = f2bf(ar[2 * s].w);
        pk.u[4] = f2bf(ar[2 * s + 1].x); pk.u[5] = f2bf(ar[2 * s + 1].y);
        pk.u[6] = f2bf(ar[2 * s + 1].z); pk.u[7] = f2bf(ar[2 * s + 1].w);
        *(bf16x8*)(lsA[cur ^ 1] + ldsOff[s]) = pk.v;
      }
      LGKM0();
    }
    CFENCE(); __builtin_amdgcn_s_barrier(); CFENCE();  // writes visible
  }

  // epilogue: rows-outer, bias hoisted
  float bv[4];
#pragma unroll
  for (int j2 = 0; j2 < 4; ++j2) bv[j2] = bias[colStart + wn + j2 * 16 + l16];
#pragma unroll
  for (int i = 0; i < 4; ++i)
#pragma unroll
    for (int r2 = 0; r2 < 4; ++r2) {
      const int row = rowStart + wm + i * 16 + quad * 4 + r2;
      const int grow = row + (row >> 10) + 1;   // b*1024+p -> b*1025+p+1
      unsigned short* go = G + (size_t)grow * 1024 + colStart + wn + l16;
#pragma unroll
      for (int j2 = 0; j2 < 4; ++j2)
        go[j2 * 16] = f2bf(gelu_exact(acc[i][j2][r2] + bv[j2]) * 32.0f);
    }
}

// --------------------------- GEMM2 (R4 core) -------------------------------
// C[M,N] = A[M,K]*B[N,K]^T. 128x128 tile, BK=64, 4 waves x (4x4) 16x16x32.
__device__ __forceinline__ void stage_tile2(
    const unsigned short* __restrict__ A, const unsigned short* __restrict__ B,
    int rowStart, int colStart, int k0, int g0,
    unsigned short* la, unsigned short* lb) {
#pragma unroll
  for (int s = 0; s < 4; ++s) {
    const int g = g0 + s * 64;
    const int r = g >> 3;
    const int slot = g & 7;
    const int kc = (slot ^ (r & 7)) << 3;
    gl_lds16(A + (size_t)(rowStart + r) * 1024 + (k0 + kc), la + g * 8);
    gl_lds16(B + (size_t)(colStart + r) * 1024 + (k0 + kc), lb + g * 8);
  }
}

__global__ __launch_bounds__(256) void gemm2_bt(
    const unsigned short* __restrict__ A, const unsigned short* __restrict__ B,
    const float* __restrict__ bias, float* __restrict__ Cf,
    const float* __restrict__ pos, int Mvalid) {
  __shared__ __align__(16) unsigned short lsA[2][8192];
  __shared__ __align__(16) unsigned short lsB[2][8192];
  const int tid = threadIdx.x;
  const int lane = tid & 63;
  const int w = tid >> 6;
  const int quad = lane >> 4;
  const int l16 = lane & 15;

  // R4 swizzle: 257 row-blocks; extra block round-robined per XCD.
  const int L = blockIdx.x;
  const int xcd = L & 7;
  const int j = L >> 3;
  int rowBlk, colBlk;
  if (j >= 256) { rowBlk = 256; colBlk = xcd; }
  else { rowBlk = xcd * 32 + (j >> 3); colBlk = j & 7; }
  const int rowStart = rowBlk * 128;
  const int colStart = colBlk * 128;
  const int wm = (w >> 1) * 64;
  const int wn = (w & 1) * 64;

  f32x4 acc[4][4];
  const f32x4 z = {0.f, 0.f, 0.f, 0.f};
#pragma unroll
  for (int i = 0; i < 4; ++i)
#pragma unroll
    for (int j2 = 0; j2 < 4; ++j2) acc[i][j2] = z;

  const int g0 = w * 256 + lane;
  stage_tile2(A, B, rowStart, colStart, 0, g0, lsA[0], lsB[0]);

  for (int t = 0; t < 16; ++t) {
    const int cur = t & 1;
    if (t + 1 < 16) {
      stage_tile2(A, B, rowStart, colStart, (t + 1) * 64, g0,
                  lsA[cur ^ 1], lsB[cur ^ 1]);
      VMCNT(8);
    } else {
      VMCNT(0);
    }
    __builtin_amdgcn_s_barrier();
    CFENCE();

    const unsigned short* cA = lsA[cur];
    const unsigned short* cB = lsB[cur];
#pragma unroll
    for (int kk = 0; kk < 64; kk += 32) {
      bf16x8 af[4], bfr[4];
      const int kcb = (kk >> 3) + quad;
#pragma unroll
      for (int i = 0; i < 4; ++i) {
        const int r = wm + i * 16 + l16;
        af[i] = *(const bf16x8*)(cA + r * 64 + ((kcb ^ (r & 7)) << 3));
      }
#pragma unroll
      for (int j2 = 0; j2 < 4; ++j2) {
        const int r = wn + j2 * 16 + l16;
        bfr[j2] = *(const bf16x8*)(cB + r * 64 + ((kcb ^ (r & 7)) << 3));
      }
#pragma unroll
      for (int i = 0; i < 4; ++i)
#pragma unroll
        for (int j2 = 0; j2 < 4; ++j2)
          acc[i][j2] = __builtin_amdgcn_mfma_f32_16x16x32_bf16(af[i], bfr[j2],
                                                               acc[i][j2], 0, 0, 0);
    }

    CFENCE();
    __builtin_amdgcn_s_barrier();
    CFENCE();
  }

  // epilogue: rows-outer, % and pointers hoisted per row, bias preloaded
  float bv[4];
#pragma unroll
  for (int j2 = 0; j2 < 4; ++j2) bv[j2] = bias[colStart + wn + j2 * 16 + l16];
#pragma unroll
  for (int i = 0; i < 4; ++i)
#pragma unroll
    for (int r2 = 0; r2 < 4; ++r2) {
      const int row = rowStart + wm + i * 16 + quad * 4 + r2;
      if (row < Mvalid) {
        const int p = row % 1025;
        const float* pr = pos + (size_t)p * 1024 + colStart + wn + l16;
        float* co = Cf + (size_t)row * 1024 + colStart + wn + l16;
#pragma unroll
        for (int j2 = 0; j2 < 4; ++j2)
          co[j2 * 16] = acc[i][j2][r2] + bv[j2] + pr[j2 * 16];
      }
    }
}

// --------------------------- launcher --------------------------------------

extern "C" void kernel_launch(void* const* d_in, const int* in_sizes, int n_in,
                              void* d_out, int out_size, void* d_ws, size_t ws_size,
                              hipStream_t stream) {
  const float* spikes  = (const float*)d_in[0];
  const float* W_embed = (const float*)d_in[1];
  const float* b_embed = (const float*)d_in[2];
  const float* cls     = (const float*)d_in[3];
  const float* W_proj  = (const float*)d_in[4];
  const float* b_proj  = (const float*)d_in[5];
  const float* pos     = (const float*)d_in[6];
  float* out = (float*)d_out;

  char* ws = (char*)d_ws;
  unsigned short* G  = (unsigned short*)(ws + 33554432);   // 64.25 MiB
  unsigned short* WE = (unsigned short*)(ws + 100925440);  // 1 MiB
  unsigned short* WP = (unsigned short*)(ws + 101974016);  // 2 MiB

  hipLaunchKernelGGL(cast_f32_bf16, dim3(2048), dim3(256), 0, stream, W_embed, WE, 524288);
  hipLaunchKernelGGL(cast_f32_bf16, dim3(4096), dim3(256), 0, stream, W_proj, WP, 1048576);
  hipLaunchKernelGGL(g0_and_pad, dim3(384), dim3(256), 0, stream, cls, G);
  hipLaunchKernelGGL(mask_stamp, dim3(129), dim3(256), 0, stream, out);

  // GEMM1 (fused patchify): spikes -> gelu*32 -> G (bf16), 2048 blocks
  hipLaunchKernelGGL(gemm1_fused, dim3(2048), dim3(256), 0, stream,
                     spikes, WE, b_embed, G);
  // GEMM2: [32896,1024] x [1024,1024]^T -> +b_proj +pos -> out (f32), 2056 blocks
  hipLaunchKernelGGL(gemm2_bt, dim3(2056), dim3(256), 0, stream,
                     G, WP, b_proj, out, pos, 32800);
}